// Round 3
// baseline (1086.531 us; speedup 1.0000x reference)
//
#include <hip/hip_runtime.h>

#define SQ 1024

typedef __attribute__((ext_vector_type(8))) short short8;
typedef __attribute__((ext_vector_type(4))) float f32x4;

#define MFMA16(a,b,c) __builtin_amdgcn_mfma_f32_16x16x32_bf16((a),(b),(c),0,0,0)

static __device__ __forceinline__ float bf2f(unsigned short u){
  union { unsigned int i; float f; } v; v.i = ((unsigned int)u) << 16; return v.f;
}
static __device__ __forceinline__ unsigned short f2bf(float f){
  union { float fv; unsigned int i; } v; v.fv = f;
  unsigned int r = v.i + 0x7fffu + ((v.i >> 16) & 1u);
  return (unsigned short)(r >> 16);
}
static __device__ __forceinline__ void split_store(float val, unsigned short* hi, unsigned short* lo, int idx){
  unsigned short h = f2bf(val);
  hi[idx] = h;
  lo[idx] = f2bf(val - bf2f(h));
}

#define COMP4(v,e) ((e)==0?(v).x:(e)==1?(v).y:(e)==2?(v).z:(v).w)

// ---------------- prep: weight transpose + bf16 hi/lo split ----------------
__global__ __launch_bounds__(256) void prep_wt(
    const float* __restrict__ Wq, const float* __restrict__ Wk,
    const float* __restrict__ Wv, const float* __restrict__ Wg,
    const float* __restrict__ Wo,
    unsigned short* __restrict__ wt_hi, unsigned short* __restrict__ wt_lo){
  __shared__ __align__(16) float tile[32][33];
  int nt = blockIdx.x * 32, kt = blockIdx.y * 32;
  int nb = nt / 384;
  const float* W = (nb==0)?Wq:(nb==1)?Wk:(nb==2)?Wv:(nb==3)?Wg:Wo;
  int nn0 = nt - nb*384;
  #pragma unroll
  for (int yy=0; yy<4; yy++){
    int k = kt + threadIdx.y + yy*8;
    tile[threadIdx.y + yy*8][threadIdx.x] = W[k*384 + nn0 + threadIdx.x];
  }
  __syncthreads();
  #pragma unroll
  for (int yy=0; yy<4; yy++){
    int n = nt + threadIdx.y + yy*8;
    int k = kt + threadIdx.x;
    float v = tile[threadIdx.x][threadIdx.y + yy*8];
    split_store(v, wt_hi, wt_lo, n*384 + k);
  }
}

// ww20[c][20]: first 12 = w_z[c]*Wz[c][h], rest 0. 80B rows -> 16B-aligned b128 reads.
__global__ __launch_bounds__(256) void prep_ww(
    const float* __restrict__ wz, const float* __restrict__ Wz, float* __restrict__ ww){
  int idx = blockIdx.x*256 + threadIdx.x;
  if (idx < 2560){
    int c = idx / 20, x = idx - c*20;
    ww[idx] = (x < 12) ? wz[c]*Wz[c*12 + x] : 0.f;
  }
}

// ---------------- rmsnorm of s -> hi/lo bf16 ----------------
__global__ __launch_bounds__(256) void rmsnorm_s(
    const float* __restrict__ s, const float* __restrict__ w,
    unsigned short* __restrict__ hi, unsigned short* __restrict__ lo){
  int wv = threadIdx.x >> 6, lane = threadIdx.x & 63;
  int row = blockIdx.x*4 + wv;
  const float* sr = s + row*384;
  float v[6]; float ss = 0.f;
  #pragma unroll
  for (int t=0;t<6;t++){ v[t] = sr[lane + t*64]; ss += v[t]*v[t]; }
  #pragma unroll
  for (int m=1;m<64;m<<=1) ss += __shfl_xor(ss, m);
  float rs = rsqrtf(ss*(1.f/384.f) + 1e-5f);
  #pragma unroll
  for (int t=0;t<6;t++){
    int c = lane + t*64;
    split_store(v[t]*rs*w[c], hi, lo, row*384 + c);
  }
}

// ---------------- GEMM1: s_n @ [Wq|Wk|Wv|Wg], hi/lo 3-MFMA ----------------
__global__ __launch_bounds__(256) void gemm_qkvg(
    const unsigned short* __restrict__ Ah, const unsigned short* __restrict__ Al,
    const unsigned short* __restrict__ Bh, const unsigned short* __restrict__ Bl,
    const float* __restrict__ bg,
    unsigned short* __restrict__ q_hi, unsigned short* __restrict__ q_lo,
    unsigned short* __restrict__ k_hi, unsigned short* __restrict__ k_lo,
    unsigned short* __restrict__ v_hi, unsigned short* __restrict__ v_lo,
    float* __restrict__ g){
  __shared__ __align__(16) unsigned short lah[64*40], lal[64*40], lbh[64*40], lbl[64*40];
  int t = threadIdx.x, wv = t >> 6, lane = t & 63;
  int m0 = blockIdx.y * 64, n0 = blockIdx.x * 64;
  int fr = lane & 15, fg = lane >> 4;
  f32x4 z4 = {0.f,0.f,0.f,0.f};
  f32x4 acc[4] = {z4, z4, z4, z4};
  int sr = t >> 2, sc = (t & 3) << 3;
  for (int k0 = 0; k0 < 384; k0 += 32){
    *(short8*)&lah[sr*40 + sc] = *(const short8*)&Ah[(m0+sr)*384 + k0 + sc];
    *(short8*)&lal[sr*40 + sc] = *(const short8*)&Al[(m0+sr)*384 + k0 + sc];
    *(short8*)&lbh[sr*40 + sc] = *(const short8*)&Bh[(n0+sr)*384 + k0 + sc];
    *(short8*)&lbl[sr*40 + sc] = *(const short8*)&Bl[(n0+sr)*384 + k0 + sc];
    __syncthreads();
    short8 a_h = *(short8*)&lah[(wv*16+fr)*40 + (fg<<3)];
    short8 a_l = *(short8*)&lal[(wv*16+fr)*40 + (fg<<3)];
    #pragma unroll
    for (int cf=0; cf<4; cf++){
      short8 b_h = *(short8*)&lbh[(cf*16+fr)*40 + (fg<<3)];
      short8 b_l = *(short8*)&lbl[(cf*16+fr)*40 + (fg<<3)];
      acc[cf] = MFMA16(a_h, b_h, acc[cf]);
      acc[cf] = MFMA16(a_h, b_l, acc[cf]);
      acc[cf] = MFMA16(a_l, b_h, acc[cf]);
    }
    __syncthreads();
  }
  int sec = n0 / 384;
  int nb0 = n0 - sec*384;
  #pragma unroll
  for (int cf=0; cf<4; cf++){
    #pragma unroll
    for (int jj=0; jj<4; jj++){
      int row = m0 + wv*16 + (fg<<2) + jj;
      int nn = nb0 + cf*16 + fr;
      float val = acc[cf][jj];
      int hh = nn >> 5, dd = nn & 31;
      if (sec == 0)      split_store(val, q_hi, q_lo, (hh<<15) + (row<<5) + dd);
      else if (sec == 1) split_store(val, k_hi, k_lo, (hh<<15) + (row<<5) + dd);
      else if (sec == 2) split_store(val, v_hi, v_lo, (hh<<15) + dd*SQ + row);  // V transposed [h][d][j]
      else               g[row*384 + nn] = val + bg[nn];
    }
  }
}

// ---------------- bias kernel v3: quad-per-row, R=4 row register blocking ----------------
// 4 threads per z-row (c4 = lane&3 owns cols c4*4+e+16*cc). No z LDS, no barriers
// in the stream; rmsnorm + head-proj partials reduced across the quad by shfl_xor.
// Each thread handles 4 rows (stride 64) so each ww b128 broadcast read feeds 4 FMA
// groups -> LDS pipe ~31us aggregate << 81us HBM floor. 1-deep z prefetch.
__global__ __launch_bounds__(256,4) void bias_k(
    const float* __restrict__ z, const int* __restrict__ zm,
    const float* __restrict__ ww, float* __restrict__ bias){
  __shared__ __align__(16) float wwl[2560];
  int t = threadIdx.x;
  for (int idx = t; idx < 2560; idx += 256) wwl[idx] = ww[idx];
  __syncthreads();

  int bid = blockIdx.x;
  int i  = bid >> 2;
  int j0 = (bid & 3) << 8;          // 256 rows per block
  int q  = t >> 2;                  // quad id 0..63
  int c4 = t & 3;

  // rows handled by this thread: j = j0 + 64*r + q, r=0..3
  const float* zb = z + ((size_t)i * SQ + j0 + q) * 128 + (c4 << 2);
  const size_t RSTR = (size_t)64 * 128;   // 64-row stride in floats

  float4 cur0 = *(const float4*)(zb);
  float4 cur1 = *(const float4*)(zb + RSTR);
  float4 cur2 = *(const float4*)(zb + 2*RSTR);
  float4 cur3 = *(const float4*)(zb + 3*RSTR);

  float ssq[4] = {0.f,0.f,0.f,0.f};
  float acc[4][12];
  #pragma unroll
  for (int r=0;r<4;r++){
    #pragma unroll
    for (int h=0;h<12;h++) acc[r][h]=0.f;
  }

  #pragma unroll
  for (int cc=0; cc<8; cc++){
    float4 nxt0, nxt1, nxt2, nxt3;
    if (cc < 7){
      const float* np = zb + (cc+1)*16;
      nxt0 = *(const float4*)(np);
      nxt1 = *(const float4*)(np + RSTR);
      nxt2 = *(const float4*)(np + 2*RSTR);
      nxt3 = *(const float4*)(np + 3*RSTR);
    }
    #pragma unroll
    for (int e=0; e<4; e++){
      int col = (cc<<4) + (c4<<2) + e;
      const float* wp = &wwl[col*20];
      float4 w0 = *(const float4*)wp;
      float4 w1 = *(const float4*)(wp+4);
      float4 w2 = *(const float4*)(wp+8);
      #pragma unroll
      for (int r=0;r<4;r++){
        float zc = COMP4((r==0?cur0:r==1?cur1:r==2?cur2:cur3), e);
        ssq[r] = fmaf(zc, zc, ssq[r]);
        acc[r][0]=fmaf(zc,w0.x,acc[r][0]);  acc[r][1]=fmaf(zc,w0.y,acc[r][1]);
        acc[r][2]=fmaf(zc,w0.z,acc[r][2]);  acc[r][3]=fmaf(zc,w0.w,acc[r][3]);
        acc[r][4]=fmaf(zc,w1.x,acc[r][4]);  acc[r][5]=fmaf(zc,w1.y,acc[r][5]);
        acc[r][6]=fmaf(zc,w1.z,acc[r][6]);  acc[r][7]=fmaf(zc,w1.w,acc[r][7]);
        acc[r][8]=fmaf(zc,w2.x,acc[r][8]);  acc[r][9]=fmaf(zc,w2.y,acc[r][9]);
        acc[r][10]=fmaf(zc,w2.z,acc[r][10]); acc[r][11]=fmaf(zc,w2.w,acc[r][11]);
      }
    }
    if (cc < 7){ cur0=nxt0; cur1=nxt1; cur2=nxt2; cur3=nxt3; }
  }

  #pragma unroll
  for (int r=0;r<4;r++){
    float ss = ssq[r];
    ss += __shfl_xor(ss,1); ss += __shfl_xor(ss,2);
    float rs = rsqrtf(ss*(1.0f/128.0f) + 1e-5f);
    #pragma unroll
    for (int h=0;h<12;h++){
      float a = acc[r][h];
      a += __shfl_xor(a,1); a += __shfl_xor(a,2);
      acc[r][h] = a;                 // all 4 quad lanes hold the full sum
    }
    int j = j0 + (r<<6) + q;
    float mk = (zm[i*SQ + j] != 0) ? 0.0f : -1.0e9f;
    size_t base = (size_t)i*SQ + j;
    #pragma unroll
    for (int hh=0; hh<3; hh++){
      int h = c4*3 + hh;             // each quad lane writes 3 of the 12 heads
      bias[(size_t)h*((size_t)SQ*SQ) + base] = fmaf(acc[r][h], rs, mk);
    }
  }
}

// ---------------- attention: wave-private 4 rows, no barriers ----------------
__global__ __launch_bounds__(256) void attn_k(
    const unsigned short* __restrict__ qh_, const unsigned short* __restrict__ ql_,
    const unsigned short* __restrict__ kh_, const unsigned short* __restrict__ kl_,
    const unsigned short* __restrict__ vh_, const unsigned short* __restrict__ vl_,
    const float* __restrict__ bias,
    unsigned short* __restrict__ oh_, unsigned short* __restrict__ ol_){
  __shared__ __align__(16) float Sl[16][SQ];   // exactly 64 KB, rows wave-private
  int t = threadIdx.x, wv = t >> 6, lane = t & 63;
  int h = blockIdx.x >> 6;
  int i0 = (blockIdx.x & 63) << 4;
  int fr = lane & 15, fg = lane >> 4;
  int hbase = h << 15;
  const unsigned short* qh = qh_ + hbase; const unsigned short* ql = ql_ + hbase;
  const unsigned short* kh = kh_ + hbase; const unsigned short* kl = kl_ + hbase;
  const unsigned short* vh = vh_ + hbase; const unsigned short* vl = vl_ + hbase;
  int r0 = i0 + (wv << 2);

  short8 aqh = {0,0,0,0,0,0,0,0}, aql = {0,0,0,0,0,0,0,0};
  if (fr < 4){
    aqh = *(const short8*)&qh[((r0 + fr) << 5) + (fg << 3)];
    aql = *(const short8*)&ql[((r0 + fr) << 5) + (fg << 3)];
  }
  const float scale = 0.17677669529663687f;  // 1/sqrt(32)

  // QK^T (hi/lo 3-MFMA) + bias + mask -> Sl
  for (int jt = 0; jt < 64; jt++){
    int j0 = jt << 4;
    short8 bkh = *(const short8*)&kh[((j0 + fr) << 5) + (fg << 3)];
    short8 bkl = *(const short8*)&kl[((j0 + fr) << 5) + (fg << 3)];
    f32x4 a = {0.f,0.f,0.f,0.f};
    a = MFMA16(aqh, bkh, a);
    a = MFMA16(aqh, bkl, a);
    a = MFMA16(aql, bkh, a);
    if (lane < 16){
      #pragma unroll
      for (int rr=0; rr<4; rr++){
        float b = bias[(size_t)h*((size_t)SQ*SQ) + (size_t)(r0+rr)*SQ + j0 + lane];
        Sl[(wv<<2)+rr][j0+lane] = fmaf(a[rr], scale, b);
      }
    }
  }

  // softmax: row = fg (4 rows/wave, 16 lanes/row); bank-rotated scans
  float* Sr = &Sl[(wv<<2)+fg][0];
  float mx = -3.0e38f;
  for (int tt=0; tt<64; tt++){
    int j = (fr + (tt<<4) + (fg<<3)) & 1023;
    mx = fmaxf(mx, Sr[j]);
  }
  mx = fmaxf(mx, __shfl_xor(mx, 1));
  mx = fmaxf(mx, __shfl_xor(mx, 2));
  mx = fmaxf(mx, __shfl_xor(mx, 4));
  mx = fmaxf(mx, __shfl_xor(mx, 8));
  float sm = 0.f;
  for (int tt=0; tt<64; tt++){
    int j = (fr + (tt<<4) + (fg<<3)) & 1023;
    float e = __expf(Sr[j] - mx);
    sm += e;
    Sr[j] = e;   // store unnormalized P (fp32)
  }
  sm += __shfl_xor(sm, 1);
  sm += __shfl_xor(sm, 2);
  sm += __shfl_xor(sm, 4);
  sm += __shfl_xor(sm, 8);
  float linv = 1.0f / sm;
  float li0 = __shfl(linv, 0), li1 = __shfl(linv, 16), li2 = __shfl(linv, 32), li3 = __shfl(linv, 48);

  // PV (hi/lo 3-MFMA), exp values read from LDS, split to bf16 on the fly
  f32x4 o0 = {0.f,0.f,0.f,0.f}, o1 = {0.f,0.f,0.f,0.f};
  for (int k0 = 0; k0 < SQ; k0 += 32){
    float4 pa = {0.f,0.f,0.f,0.f}, pb = {0.f,0.f,0.f,0.f};
    if (fr < 4){
      const float* pp = &Sl[(wv<<2)+fr][k0 + (fg<<3)];
      pa = *(const float4*)pp;
      pb = *(const float4*)(pp+4);
    }
    short8 ph = {0,0,0,0,0,0,0,0}, pl = {0,0,0,0,0,0,0,0};
    #pragma unroll
    for (int e2=0; e2<8; e2++){
      float pv = (e2 < 4) ? COMP4(pa, e2) : COMP4(pb, (e2-4));
      unsigned short hbv = f2bf(pv);
      ph[e2] = (short)hbv;
      pl[e2] = (short)f2bf(pv - bf2f(hbv));
    }
    short8 v0h = *(const short8*)&vh[(fr)*SQ + k0 + (fg<<3)];
    short8 v0l = *(const short8*)&vl[(fr)*SQ + k0 + (fg<<3)];
    short8 v1h = *(const short8*)&vh[(16+fr)*SQ + k0 + (fg<<3)];
    short8 v1l = *(const short8*)&vl[(16+fr)*SQ + k0 + (fg<<3)];
    o0 = MFMA16(ph, v0h, o0); o0 = MFMA16(ph, v0l, o0); o0 = MFMA16(pl, v0h, o0);
    o1 = MFMA16(ph, v1h, o1); o1 = MFMA16(ph, v1l, o1); o1 = MFMA16(pl, v1h, o1);
  }
  float liA[4] = {li0, li1, li2, li3};
  if (lane < 16){
    #pragma unroll
    for (int rr=0; rr<4; rr++){
      int orow = r0 + rr;
      float va = o0[rr] * liA[rr];
      float vb = o1[rr] * liA[rr];
      split_store(va, oh_, ol_, orow*384 + (h<<5) + fr);
      split_store(vb, oh_, ol_, orow*384 + (h<<5) + 16 + fr);
    }
  }
}

// ---------------- GEMM2: (o @ Wo + bo) * g -> fp32 out ----------------
__global__ __launch_bounds__(256) void gemm_out_k(
    const unsigned short* __restrict__ Ah, const unsigned short* __restrict__ Al,
    const unsigned short* __restrict__ Bh, const unsigned short* __restrict__ Bl,
    const float* __restrict__ bo, const float* __restrict__ g,
    float* __restrict__ out){
  __shared__ __align__(16) unsigned short lah[64*40], lal[64*40], lbh[64*40], lbl[64*40];
  int t = threadIdx.x, wv = t >> 6, lane = t & 63;
  int m0 = blockIdx.y * 64, n0 = blockIdx.x * 64;
  int fr = lane & 15, fg = lane >> 4;
  f32x4 z4 = {0.f,0.f,0.f,0.f};
  f32x4 acc[4] = {z4, z4, z4, z4};
  int sr = t >> 2, sc = (t & 3) << 3;
  for (int k0 = 0; k0 < 384; k0 += 32){
    *(short8*)&lah[sr*40 + sc] = *(const short8*)&Ah[(m0+sr)*384 + k0 + sc];
    *(short8*)&lal[sr*40 + sc] = *(const short8*)&Al[(m0+sr)*384 + k0 + sc];
    *(short8*)&lbh[sr*40 + sc] = *(const short8*)&Bh[(n0+sr)*384 + k0 + sc];
    *(short8*)&lbl[sr*40 + sc] = *(const short8*)&Bl[(n0+sr)*384 + k0 + sc];
    __syncthreads();
    short8 a_h = *(short8*)&lah[(wv*16+fr)*40 + (fg<<3)];
    short8 a_l = *(short8*)&lal[(wv*16+fr)*40 + (fg<<3)];
    #pragma unroll
    for (int cf=0; cf<4; cf++){
      short8 b_h = *(short8*)&lbh[(cf*16+fr)*40 + (fg<<3)];
      short8 b_l = *(short8*)&lbl[(cf*16+fr)*40 + (fg<<3)];
      acc[cf] = MFMA16(a_h, b_h, acc[cf]);
      acc[cf] = MFMA16(a_h, b_l, acc[cf]);
      acc[cf] = MFMA16(a_l, b_h, acc[cf]);
    }
    __syncthreads();
  }
  #pragma unroll
  for (int cf=0; cf<4; cf++){
    #pragma unroll
    for (int jj=0; jj<4; jj++){
      int row = m0 + wv*16 + (fg<<2) + jj;
      int col = n0 + cf*16 + fr;
      out[row*384 + col] = (acc[cf][jj] + bo[col]) * g[row*384 + col];
    }
  }
}

// ---------------- launch ----------------
extern "C" void kernel_launch(void* const* d_in, const int* in_sizes, int n_in,
                              void* d_out, int out_size, void* d_ws, size_t ws_size,
                              hipStream_t stream) {
  const float* s   = (const float*)d_in[0];
  const float* z   = (const float*)d_in[1];
  const int*   zm  = (const int*)d_in[2];
  const float* w_s = (const float*)d_in[3];
  const float* w_z = (const float*)d_in[4];
  const float* Wz  = (const float*)d_in[5];
  const float* Wq  = (const float*)d_in[6];
  const float* Wk  = (const float*)d_in[7];
  const float* Wv  = (const float*)d_in[8];
  const float* Wg  = (const float*)d_in[9];
  const float* bg  = (const float*)d_in[10];
  const float* Wo  = (const float*)d_in[11];
  const float* bo  = (const float*)d_in[12];
  float* out = (float*)d_out;
  char* ws = (char*)d_ws;

  unsigned short* s_hi  = (unsigned short*)(ws + 0);
  unsigned short* s_lo  = (unsigned short*)(ws + 786432);
  unsigned short* wt_hi = (unsigned short*)(ws + 1572864);   // [1920][384]
  unsigned short* wt_lo = (unsigned short*)(ws + 3047424);
  float*          ww    = (float*)(ws + 4521984);            // [128][20] fp32
  unsigned short* q_hi  = (unsigned short*)(ws + 4532224);   // [12][1024][32]
  unsigned short* q_lo  = (unsigned short*)(ws + 5318656);
  unsigned short* k_hi  = (unsigned short*)(ws + 6105088);
  unsigned short* k_lo  = (unsigned short*)(ws + 6891520);
  unsigned short* v_hi  = (unsigned short*)(ws + 7677952);   // [12][32][1024] (transposed)
  unsigned short* v_lo  = (unsigned short*)(ws + 8464384);
  float*          gbuf  = (float*)(ws + 9250816);            // [1024][384] fp32
  unsigned short* o_hi  = (unsigned short*)(ws + 10823680);  // [1024][384]
  unsigned short* o_lo  = (unsigned short*)(ws + 11610112);
  float*          biasb = (float*)(ws + 12396544);           // [12][1024][1024] fp32, 48MB

  prep_wt<<<dim3(60,12), dim3(32,8), 0, stream>>>(Wq, Wk, Wv, Wg, Wo, wt_hi, wt_lo);
  prep_ww<<<10, 256, 0, stream>>>(w_z, Wz, ww);
  rmsnorm_s<<<256, 256, 0, stream>>>(s, w_s, s_hi, s_lo);
  gemm_qkvg<<<dim3(24,16), 256, 0, stream>>>(s_hi, s_lo, wt_hi, wt_lo, bg,
                                             q_hi, q_lo, k_hi, k_lo, v_hi, v_lo, gbuf);
  bias_k<<<4096, 256, 0, stream>>>(z, zm, ww, biasb);
  attn_k<<<768, 256, 0, stream>>>(q_hi, q_lo, k_hi, k_lo, v_hi, v_lo, biasb, o_hi, o_lo);
  gemm_out_k<<<dim3(6,16), 256, 0, stream>>>(o_hi, o_lo,
                                             wt_hi + 1536*384, wt_lo + 1536*384,
                                             bo, gbuf, out);
}

// Round 4
// 384.482 us; speedup vs baseline: 2.8260x; 2.8260x over previous
//
#include <hip/hip_runtime.h>

#define SQ 1024

typedef __attribute__((ext_vector_type(8))) short short8;
typedef __attribute__((ext_vector_type(4))) float f32x4;

#define MFMA16(a,b,c) __builtin_amdgcn_mfma_f32_16x16x32_bf16((a),(b),(c),0,0,0)

static __device__ __forceinline__ float bf2f(unsigned short u){
  union { unsigned int i; float f; } v; v.i = ((unsigned int)u) << 16; return v.f;
}
static __device__ __forceinline__ unsigned short f2bf(float f){
  union { float fv; unsigned int i; } v; v.fv = f;
  unsigned int r = v.i + 0x7fffu + ((v.i >> 16) & 1u);
  return (unsigned short)(r >> 16);
}
static __device__ __forceinline__ void split_store(float val, unsigned short* hi, unsigned short* lo, int idx){
  unsigned short h = f2bf(val);
  hi[idx] = h;
  lo[idx] = f2bf(val - bf2f(h));
}

#define COMP4(v,e) ((e)==0?(v).x:(e)==1?(v).y:(e)==2?(v).z:(v).w)

// async global->LDS, 4 bytes per lane (dest = uniform base + lane*4)
static __device__ __forceinline__ void gld_lds4(const float* g, float* d){
  __builtin_amdgcn_global_load_lds(
    static_cast<const unsigned int __attribute__((address_space(1)))*>(
        (const void __attribute__((address_space(1)))*)g),
    static_cast<unsigned int __attribute__((address_space(3)))*>(
        (void __attribute__((address_space(3)))*)d),
    4, 0, 0);
}

// ---------------- prep: weight transpose + bf16 hi/lo split ----------------
__global__ __launch_bounds__(256) void prep_wt(
    const float* __restrict__ Wq, const float* __restrict__ Wk,
    const float* __restrict__ Wv, const float* __restrict__ Wg,
    const float* __restrict__ Wo,
    unsigned short* __restrict__ wt_hi, unsigned short* __restrict__ wt_lo){
  __shared__ __align__(16) float tile[32][33];
  int nt = blockIdx.x * 32, kt = blockIdx.y * 32;
  int nb = nt / 384;
  const float* W = (nb==0)?Wq:(nb==1)?Wk:(nb==2)?Wv:(nb==3)?Wg:Wo;
  int nn0 = nt - nb*384;
  #pragma unroll
  for (int yy=0; yy<4; yy++){
    int k = kt + threadIdx.y + yy*8;
    tile[threadIdx.y + yy*8][threadIdx.x] = W[k*384 + nn0 + threadIdx.x];
  }
  __syncthreads();
  #pragma unroll
  for (int yy=0; yy<4; yy++){
    int n = nt + threadIdx.y + yy*8;
    int k = kt + threadIdx.x;
    float v = tile[threadIdx.x][threadIdx.y + yy*8];
    split_store(v, wt_hi, wt_lo, n*384 + k);
  }
}

// ww20[c][20]: first 12 = w_z[c]*Wz[c][h], rest 0. 80B rows -> 16B-aligned b128 reads.
__global__ __launch_bounds__(256) void prep_ww(
    const float* __restrict__ wz, const float* __restrict__ Wz, float* __restrict__ ww){
  int idx = blockIdx.x*256 + threadIdx.x;
  if (idx < 2560){
    int c = idx / 20, x = idx - c*20;
    ww[idx] = (x < 12) ? wz[c]*Wz[c*12 + x] : 0.f;
  }
}

// ---------------- rmsnorm of s -> hi/lo bf16 ----------------
__global__ __launch_bounds__(256) void rmsnorm_s(
    const float* __restrict__ s, const float* __restrict__ w,
    unsigned short* __restrict__ hi, unsigned short* __restrict__ lo){
  int wv = threadIdx.x >> 6, lane = threadIdx.x & 63;
  int row = blockIdx.x*4 + wv;
  const float* sr = s + row*384;
  float v[6]; float ss = 0.f;
  #pragma unroll
  for (int t=0;t<6;t++){ v[t] = sr[lane + t*64]; ss += v[t]*v[t]; }
  #pragma unroll
  for (int m=1;m<64;m<<=1) ss += __shfl_xor(ss, m);
  float rs = rsqrtf(ss*(1.f/384.f) + 1e-5f);
  #pragma unroll
  for (int t=0;t<6;t++){
    int c = lane + t*64;
    split_store(v[t]*rs*w[c], hi, lo, row*384 + c);
  }
}

// ---------------- GEMM1: s_n @ [Wq|Wk|Wv|Wg], hi/lo 3-MFMA ----------------
__global__ __launch_bounds__(256) void gemm_qkvg(
    const unsigned short* __restrict__ Ah, const unsigned short* __restrict__ Al,
    const unsigned short* __restrict__ Bh, const unsigned short* __restrict__ Bl,
    const float* __restrict__ bg,
    unsigned short* __restrict__ q_hi, unsigned short* __restrict__ q_lo,
    unsigned short* __restrict__ k_hi, unsigned short* __restrict__ k_lo,
    unsigned short* __restrict__ v_hi, unsigned short* __restrict__ v_lo,
    float* __restrict__ g){
  __shared__ __align__(16) unsigned short lah[64*40], lal[64*40], lbh[64*40], lbl[64*40];
  int t = threadIdx.x, wv = t >> 6, lane = t & 63;
  int m0 = blockIdx.y * 64, n0 = blockIdx.x * 64;
  int fr = lane & 15, fg = lane >> 4;
  f32x4 z4 = {0.f,0.f,0.f,0.f};
  f32x4 acc[4] = {z4, z4, z4, z4};
  int sr = t >> 2, sc = (t & 3) << 3;
  for (int k0 = 0; k0 < 384; k0 += 32){
    *(short8*)&lah[sr*40 + sc] = *(const short8*)&Ah[(m0+sr)*384 + k0 + sc];
    *(short8*)&lal[sr*40 + sc] = *(const short8*)&Al[(m0+sr)*384 + k0 + sc];
    *(short8*)&lbh[sr*40 + sc] = *(const short8*)&Bh[(n0+sr)*384 + k0 + sc];
    *(short8*)&lbl[sr*40 + sc] = *(const short8*)&Bl[(n0+sr)*384 + k0 + sc];
    __syncthreads();
    short8 a_h = *(short8*)&lah[(wv*16+fr)*40 + (fg<<3)];
    short8 a_l = *(short8*)&lal[(wv*16+fr)*40 + (fg<<3)];
    #pragma unroll
    for (int cf=0; cf<4; cf++){
      short8 b_h = *(short8*)&lbh[(cf*16+fr)*40 + (fg<<3)];
      short8 b_l = *(short8*)&lbl[(cf*16+fr)*40 + (fg<<3)];
      acc[cf] = MFMA16(a_h, b_h, acc[cf]);
      acc[cf] = MFMA16(a_h, b_l, acc[cf]);
      acc[cf] = MFMA16(a_l, b_h, acc[cf]);
    }
    __syncthreads();
  }
  int sec = n0 / 384;
  int nb0 = n0 - sec*384;
  #pragma unroll
  for (int cf=0; cf<4; cf++){
    #pragma unroll
    for (int jj=0; jj<4; jj++){
      int row = m0 + wv*16 + (fg<<2) + jj;
      int nn = nb0 + cf*16 + fr;
      float val = acc[cf][jj];
      int hh = nn >> 5, dd = nn & 31;
      if (sec == 0)      split_store(val, q_hi, q_lo, (hh<<15) + (row<<5) + dd);
      else if (sec == 1) split_store(val, k_hi, k_lo, (hh<<15) + (row<<5) + dd);
      else if (sec == 2) split_store(val, v_hi, v_lo, (hh<<15) + dd*SQ + row);  // V transposed [h][d][j]
      else               g[row*384 + nn] = val + bg[nn];
    }
  }
}

// ---------------- bias kernel v4: global_load_lds staged, wave-private dbuf ----------------
// Block = one i (1024 blocks), 4 waves. Wave w owns rows [w*256, w*256+256) in 8
// subtiles of 32 rows, double-buffered (2x16KB per wave). Staging: 64 async
// global_load_lds (4B/lane, 256B contiguous source per instr) with the global
// source pre-swizzled c' = c ^ (row&31) so linear LDS reads are bank-conflict-free.
// Lane pair (l, l+32) splits each row's 128 cols; pair-reduce via shfl_xor(32).
// Counted vmcnt(6) pipeline, no barriers in the stream (buffers wave-private).
__global__ __launch_bounds__(256) void bias_k(
    const float* __restrict__ z, const int* __restrict__ zm,
    const float* __restrict__ ww, float* __restrict__ bias){
  __shared__ __align__(16) float zbuf[4*2*4096];   // 128KB: [wave][buf][32 rows][128]
  __shared__ __align__(16) float wwl[2560];        // 10KB, [128][20]
  int t = threadIdx.x;
  int w = t >> 6, lane = t & 63;
  int l31 = lane & 31, colhalf = lane >> 5;
  int i = blockIdx.x;
  for (int idx = t; idx < 2560; idx += 256) wwl[idx] = ww[idx];
  __syncthreads();

  const float* zi = z + (size_t)i * (SQ*128);
  const int* zmi = zm + (size_t)i * SQ;
  int sperm = (lane & 32);                    // bit5 word offset of source col

  #define STAGE(ST, BUF)                                                     \
    {                                                                        \
      const float* zs = zi + (w*256 + (ST)*32)*128;                          \
      float* db = zbuf + (w*2 + (BUF))*4096;                                 \
      _Pragma("unroll 8")                                                    \
      for (int n = 0; n < 64; ++n){                                          \
        int r = n >> 1, hf = n & 1;                                          \
        gld_lds4(zs + r*128 + hf*64 + sperm + (l31 ^ r),                     \
                 db + r*128 + hf*64);                                        \
      }                                                                      \
    }

  STAGE(0, 0)
  asm volatile("s_waitcnt vmcnt(0)" ::: "memory");

  #pragma unroll 1
  for (int st = 0; st < 8; ++st){
    int zmval = zmi[w*256 + st*32 + l31];      // early: retires before epilogue
    if (st < 7){
      int stn = st + 1;
      int bn = stn & 1;
      STAGE(stn, bn)
    }
    // ---- compute subtile st from buf st&1 ----
    int tb = (w*2 + (st&1))*4096 + (l31<<7) + (colhalf<<6);
    const float* wbase = &wwl[colhalf*64*20];
    float ssq = 0.f;
    float acc[12];
    #pragma unroll
    for (int h=0;h<12;h++) acc[h] = 0.f;
    #pragma unroll 8
    for (int cc=0; cc<64; ++cc){
      float zc = zbuf[tb + (cc&32) + ((cc&31)^l31)];
      const float* wp = wbase + cc*20;
      float4 w0 = *(const float4*)wp;
      float4 w1 = *(const float4*)(wp+4);
      float4 w2 = *(const float4*)(wp+8);
      ssq = fmaf(zc, zc, ssq);
      acc[0]=fmaf(zc,w0.x,acc[0]);  acc[1]=fmaf(zc,w0.y,acc[1]);
      acc[2]=fmaf(zc,w0.z,acc[2]);  acc[3]=fmaf(zc,w0.w,acc[3]);
      acc[4]=fmaf(zc,w1.x,acc[4]);  acc[5]=fmaf(zc,w1.y,acc[5]);
      acc[6]=fmaf(zc,w1.z,acc[6]);  acc[7]=fmaf(zc,w1.w,acc[7]);
      acc[8]=fmaf(zc,w2.x,acc[8]);  acc[9]=fmaf(zc,w2.y,acc[9]);
      acc[10]=fmaf(zc,w2.z,acc[10]); acc[11]=fmaf(zc,w2.w,acc[11]);
    }
    // pair-reduce (lanes l and l+32 hold the two col-halves of the same row)
    ssq += __shfl_xor(ssq, 32);
    float rs = rsqrtf(ssq*(1.0f/128.0f) + 1e-5f);
    float mk = (zmval != 0) ? 0.0f : -1.0e9f;
    size_t base = (size_t)i*SQ + (w*256 + st*32 + l31);
    #pragma unroll
    for (int hh=0; hh<6; ++hh){
      float aLo = acc[hh]   + __shfl_xor(acc[hh],   32);
      float aHi = acc[hh+6] + __shfl_xor(acc[hh+6], 32);
      float av = colhalf ? aHi : aLo;
      bias[(size_t)(hh + colhalf*6)*((size_t)SQ*SQ) + base] = fmaf(av, rs, mk);
    }
    // stage(st+1)'s 64 loads are the oldest in queue (besides <=6 stores + 1 zm)
    asm volatile("s_waitcnt vmcnt(6)" ::: "memory");
  }
  #undef STAGE
}

// ---------------- attention: wave-private 4 rows, no barriers ----------------
__global__ __launch_bounds__(256) void attn_k(
    const unsigned short* __restrict__ qh_, const unsigned short* __restrict__ ql_,
    const unsigned short* __restrict__ kh_, const unsigned short* __restrict__ kl_,
    const unsigned short* __restrict__ vh_, const unsigned short* __restrict__ vl_,
    const float* __restrict__ bias,
    unsigned short* __restrict__ oh_, unsigned short* __restrict__ ol_){
  __shared__ __align__(16) float Sl[16][SQ];   // exactly 64 KB, rows wave-private
  int t = threadIdx.x, wv = t >> 6, lane = t & 63;
  int h = blockIdx.x >> 6;
  int i0 = (blockIdx.x & 63) << 4;
  int fr = lane & 15, fg = lane >> 4;
  int hbase = h << 15;
  const unsigned short* qh = qh_ + hbase; const unsigned short* ql = ql_ + hbase;
  const unsigned short* kh = kh_ + hbase; const unsigned short* kl = kl_ + hbase;
  const unsigned short* vh = vh_ + hbase; const unsigned short* vl = vl_ + hbase;
  int r0 = i0 + (wv << 2);

  short8 aqh = {0,0,0,0,0,0,0,0}, aql = {0,0,0,0,0,0,0,0};
  if (fr < 4){
    aqh = *(const short8*)&qh[((r0 + fr) << 5) + (fg << 3)];
    aql = *(const short8*)&ql[((r0 + fr) << 5) + (fg << 3)];
  }
  const float scale = 0.17677669529663687f;  // 1/sqrt(32)

  // QK^T (hi/lo 3-MFMA) + bias + mask -> Sl
  for (int jt = 0; jt < 64; jt++){
    int j0 = jt << 4;
    short8 bkh = *(const short8*)&kh[((j0 + fr) << 5) + (fg << 3)];
    short8 bkl = *(const short8*)&kl[((j0 + fr) << 5) + (fg << 3)];
    f32x4 a = {0.f,0.f,0.f,0.f};
    a = MFMA16(aqh, bkh, a);
    a = MFMA16(aqh, bkl, a);
    a = MFMA16(aql, bkh, a);
    if (lane < 16){
      #pragma unroll
      for (int rr=0; rr<4; rr++){
        float b = bias[(size_t)h*((size_t)SQ*SQ) + (size_t)(r0+rr)*SQ + j0 + lane];
        Sl[(wv<<2)+rr][j0+lane] = fmaf(a[rr], scale, b);
      }
    }
  }

  // softmax: row = fg (4 rows/wave, 16 lanes/row); bank-rotated scans
  float* Sr = &Sl[(wv<<2)+fg][0];
  float mx = -3.0e38f;
  for (int tt=0; tt<64; tt++){
    int j = (fr + (tt<<4) + (fg<<3)) & 1023;
    mx = fmaxf(mx, Sr[j]);
  }
  mx = fmaxf(mx, __shfl_xor(mx, 1));
  mx = fmaxf(mx, __shfl_xor(mx, 2));
  mx = fmaxf(mx, __shfl_xor(mx, 4));
  mx = fmaxf(mx, __shfl_xor(mx, 8));
  float sm = 0.f;
  for (int tt=0; tt<64; tt++){
    int j = (fr + (tt<<4) + (fg<<3)) & 1023;
    float e = __expf(Sr[j] - mx);
    sm += e;
    Sr[j] = e;   // store unnormalized P (fp32)
  }
  sm += __shfl_xor(sm, 1);
  sm += __shfl_xor(sm, 2);
  sm += __shfl_xor(sm, 4);
  sm += __shfl_xor(sm, 8);
  float linv = 1.0f / sm;
  float li0 = __shfl(linv, 0), li1 = __shfl(linv, 16), li2 = __shfl(linv, 32), li3 = __shfl(linv, 48);

  // PV (hi/lo 3-MFMA), exp values read from LDS, split to bf16 on the fly
  f32x4 o0 = {0.f,0.f,0.f,0.f}, o1 = {0.f,0.f,0.f,0.f};
  for (int k0 = 0; k0 < SQ; k0 += 32){
    float4 pa = {0.f,0.f,0.f,0.f}, pb = {0.f,0.f,0.f,0.f};
    if (fr < 4){
      const float* pp = &Sl[(wv<<2)+fr][k0 + (fg<<3)];
      pa = *(const float4*)pp;
      pb = *(const float4*)(pp+4);
    }
    short8 ph = {0,0,0,0,0,0,0,0}, pl = {0,0,0,0,0,0,0,0};
    #pragma unroll
    for (int e2=0; e2<8; e2++){
      float pv = (e2 < 4) ? COMP4(pa, e2) : COMP4(pb, (e2-4));
      unsigned short hbv = f2bf(pv);
      ph[e2] = (short)hbv;
      pl[e2] = (short)f2bf(pv - bf2f(hbv));
    }
    short8 v0h = *(const short8*)&vh[(fr)*SQ + k0 + (fg<<3)];
    short8 v0l = *(const short8*)&vl[(fr)*SQ + k0 + (fg<<3)];
    short8 v1h = *(const short8*)&vh[(16+fr)*SQ + k0 + (fg<<3)];
    short8 v1l = *(const short8*)&vl[(16+fr)*SQ + k0 + (fg<<3)];
    o0 = MFMA16(ph, v0h, o0); o0 = MFMA16(ph, v0l, o0); o0 = MFMA16(pl, v0h, o0);
    o1 = MFMA16(ph, v1h, o1); o1 = MFMA16(ph, v1l, o1); o1 = MFMA16(pl, v1h, o1);
  }
  float liA[4] = {li0, li1, li2, li3};
  if (lane < 16){
    #pragma unroll
    for (int rr=0; rr<4; rr++){
      int orow = r0 + rr;
      float va = o0[rr] * liA[rr];
      float vb = o1[rr] * liA[rr];
      split_store(va, oh_, ol_, orow*384 + (h<<5) + fr);
      split_store(vb, oh_, ol_, orow*384 + (h<<5) + 16 + fr);
    }
  }
}

// ---------------- GEMM2: (o @ Wo + bo) * g -> fp32 out ----------------
__global__ __launch_bounds__(256) void gemm_out_k(
    const unsigned short* __restrict__ Ah, const unsigned short* __restrict__ Al,
    const unsigned short* __restrict__ Bh, const unsigned short* __restrict__ Bl,
    const float* __restrict__ bo, const float* __restrict__ g,
    float* __restrict__ out){
  __shared__ __align__(16) unsigned short lah[64*40], lal[64*40], lbh[64*40], lbl[64*40];
  int t = threadIdx.x, wv = t >> 6, lane = t & 63;
  int m0 = blockIdx.y * 64, n0 = blockIdx.x * 64;
  int fr = lane & 15, fg = lane >> 4;
  f32x4 z4 = {0.f,0.f,0.f,0.f};
  f32x4 acc[4] = {z4, z4, z4, z4};
  int sr = t >> 2, sc = (t & 3) << 3;
  for (int k0 = 0; k0 < 384; k0 += 32){
    *(short8*)&lah[sr*40 + sc] = *(const short8*)&Ah[(m0+sr)*384 + k0 + sc];
    *(short8*)&lal[sr*40 + sc] = *(const short8*)&Al[(m0+sr)*384 + k0 + sc];
    *(short8*)&lbh[sr*40 + sc] = *(const short8*)&Bh[(n0+sr)*384 + k0 + sc];
    *(short8*)&lbl[sr*40 + sc] = *(const short8*)&Bl[(n0+sr)*384 + k0 + sc];
    __syncthreads();
    short8 a_h = *(short8*)&lah[(wv*16+fr)*40 + (fg<<3)];
    short8 a_l = *(short8*)&lal[(wv*16+fr)*40 + (fg<<3)];
    #pragma unroll
    for (int cf=0; cf<4; cf++){
      short8 b_h = *(short8*)&lbh[(cf*16+fr)*40 + (fg<<3)];
      short8 b_l = *(short8*)&lbl[(cf*16+fr)*40 + (fg<<3)];
      acc[cf] = MFMA16(a_h, b_h, acc[cf]);
      acc[cf] = MFMA16(a_h, b_l, acc[cf]);
      acc[cf] = MFMA16(a_l, b_h, acc[cf]);
    }
    __syncthreads();
  }
  #pragma unroll
  for (int cf=0; cf<4; cf++){
    #pragma unroll
    for (int jj=0; jj<4; jj++){
      int row = m0 + wv*16 + (fg<<2) + jj;
      int col = n0 + cf*16 + fr;
      out[row*384 + col] = (acc[cf][jj] + bo[col]) * g[row*384 + col];
    }
  }
}

// ---------------- launch ----------------
extern "C" void kernel_launch(void* const* d_in, const int* in_sizes, int n_in,
                              void* d_out, int out_size, void* d_ws, size_t ws_size,
                              hipStream_t stream) {
  const float* s   = (const float*)d_in[0];
  const float* z   = (const float*)d_in[1];
  const int*   zm  = (const int*)d_in[2];
  const float* w_s = (const float*)d_in[3];
  const float* w_z = (const float*)d_in[4];
  const float* Wz  = (const float*)d_in[5];
  const float* Wq  = (const float*)d_in[6];
  const float* Wk  = (const float*)d_in[7];
  const float* Wv  = (const float*)d_in[8];
  const float* Wg  = (const float*)d_in[9];
  const float* bg  = (const float*)d_in[10];
  const float* Wo  = (const float*)d_in[11];
  const float* bo  = (const float*)d_in[12];
  float* out = (float*)d_out;
  char* ws = (char*)d_ws;

  unsigned short* s_hi  = (unsigned short*)(ws + 0);
  unsigned short* s_lo  = (unsigned short*)(ws + 786432);
  unsigned short* wt_hi = (unsigned short*)(ws + 1572864);   // [1920][384]
  unsigned short* wt_lo = (unsigned short*)(ws + 3047424);
  float*          ww    = (float*)(ws + 4521984);            // [128][20] fp32
  unsigned short* q_hi  = (unsigned short*)(ws + 4532224);   // [12][1024][32]
  unsigned short* q_lo  = (unsigned short*)(ws + 5318656);
  unsigned short* k_hi  = (unsigned short*)(ws + 6105088);
  unsigned short* k_lo  = (unsigned short*)(ws + 6891520);
  unsigned short* v_hi  = (unsigned short*)(ws + 7677952);   // [12][32][1024] (transposed)
  unsigned short* v_lo  = (unsigned short*)(ws + 8464384);
  float*          gbuf  = (float*)(ws + 9250816);            // [1024][384] fp32
  unsigned short* o_hi  = (unsigned short*)(ws + 10823680);  // [1024][384]
  unsigned short* o_lo  = (unsigned short*)(ws + 11610112);
  float*          biasb = (float*)(ws + 12396544);           // [12][1024][1024] fp32, 48MB

  prep_wt<<<dim3(60,12), dim3(32,8), 0, stream>>>(Wq, Wk, Wv, Wg, Wo, wt_hi, wt_lo);
  prep_ww<<<10, 256, 0, stream>>>(w_z, Wz, ww);
  rmsnorm_s<<<256, 256, 0, stream>>>(s, w_s, s_hi, s_lo);
  gemm_qkvg<<<dim3(24,16), 256, 0, stream>>>(s_hi, s_lo, wt_hi, wt_lo, bg,
                                             q_hi, q_lo, k_hi, k_lo, v_hi, v_lo, gbuf);
  bias_k<<<1024, 256, 0, stream>>>(z, zm, ww, biasb);
  attn_k<<<768, 256, 0, stream>>>(q_hi, q_lo, k_hi, k_lo, v_hi, v_lo, biasb, o_hi, o_lo);
  gemm_out_k<<<dim3(6,16), 256, 0, stream>>>(o_hi, o_lo,
                                             wt_hi + 1536*384, wt_lo + 1536*384,
                                             bo, gbuf, out);
}

// Round 5
// 335.565 us; speedup vs baseline: 3.2379x; 1.1458x over previous
//
#include <hip/hip_runtime.h>

#define SQ 1024

typedef __attribute__((ext_vector_type(8))) short short8;
typedef __attribute__((ext_vector_type(4))) float f32x4;

#define MFMA16(a,b,c) __builtin_amdgcn_mfma_f32_16x16x32_bf16((a),(b),(c),0,0,0)

static __device__ __forceinline__ float bf2f(unsigned short u){
  union { unsigned int i; float f; } v; v.i = ((unsigned int)u) << 16; return v.f;
}
static __device__ __forceinline__ unsigned short f2bf(float f){
  union { float fv; unsigned int i; } v; v.fv = f;
  unsigned int r = v.i + 0x7fffu + ((v.i >> 16) & 1u);
  return (unsigned short)(r >> 16);
}
static __device__ __forceinline__ void split_store(float val, unsigned short* hi, unsigned short* lo, int idx){
  unsigned short h = f2bf(val);
  hi[idx] = h;
  lo[idx] = f2bf(val - bf2f(h));
}

#define COMP4(v,e) ((e)==0?(v).x:(e)==1?(v).y:(e)==2?(v).z:(v).w)

// async global->LDS, 16 bytes per lane (dest = uniform base + lane*16)
static __device__ __forceinline__ void gld_lds16(const float* g, float* d){
  __builtin_amdgcn_global_load_lds(
    static_cast<const unsigned int __attribute__((address_space(1)))*>(
        (const void __attribute__((address_space(1)))*)g),
    static_cast<unsigned int __attribute__((address_space(3)))*>(
        (void __attribute__((address_space(3)))*)d),
    16, 0, 0);
}

// ---------------- prep: weight transpose + bf16 hi/lo split ----------------
__global__ __launch_bounds__(256) void prep_wt(
    const float* __restrict__ Wq, const float* __restrict__ Wk,
    const float* __restrict__ Wv, const float* __restrict__ Wg,
    const float* __restrict__ Wo,
    unsigned short* __restrict__ wt_hi, unsigned short* __restrict__ wt_lo){
  __shared__ __align__(16) float tile[32][33];
  int nt = blockIdx.x * 32, kt = blockIdx.y * 32;
  int nb = nt / 384;
  const float* W = (nb==0)?Wq:(nb==1)?Wk:(nb==2)?Wv:(nb==3)?Wg:Wo;
  int nn0 = nt - nb*384;
  #pragma unroll
  for (int yy=0; yy<4; yy++){
    int k = kt + threadIdx.y + yy*8;
    tile[threadIdx.y + yy*8][threadIdx.x] = W[k*384 + nn0 + threadIdx.x];
  }
  __syncthreads();
  #pragma unroll
  for (int yy=0; yy<4; yy++){
    int n = nt + threadIdx.y + yy*8;
    int k = kt + threadIdx.x;
    float v = tile[threadIdx.x][threadIdx.y + yy*8];
    split_store(v, wt_hi, wt_lo, n*384 + k);
  }
}

// ww hi/lo bf16: [c=128][h=16], h>=12 zero. value = w_z[c]*Wz[c][h].
__global__ __launch_bounds__(256) void prep_ww(
    const float* __restrict__ wz, const float* __restrict__ Wz,
    unsigned short* __restrict__ wwh, unsigned short* __restrict__ wwl2){
  int idx = blockIdx.x*256 + threadIdx.x;
  if (idx < 2048){
    int c = idx >> 4, h = idx & 15;
    float val = (h < 12) ? wz[c]*Wz[c*12 + h] : 0.f;
    unsigned short hh = f2bf(val);
    wwh[idx] = hh;
    wwl2[idx] = f2bf(val - bf2f(hh));
  }
}

// ---------------- rmsnorm of s -> hi/lo bf16 ----------------
__global__ __launch_bounds__(256) void rmsnorm_s(
    const float* __restrict__ s, const float* __restrict__ w,
    unsigned short* __restrict__ hi, unsigned short* __restrict__ lo){
  int wv = threadIdx.x >> 6, lane = threadIdx.x & 63;
  int row = blockIdx.x*4 + wv;
  const float* sr = s + row*384;
  float v[6]; float ss = 0.f;
  #pragma unroll
  for (int t=0;t<6;t++){ v[t] = sr[lane + t*64]; ss += v[t]*v[t]; }
  #pragma unroll
  for (int m=1;m<64;m<<=1) ss += __shfl_xor(ss, m);
  float rs = rsqrtf(ss*(1.f/384.f) + 1e-5f);
  #pragma unroll
  for (int t=0;t<6;t++){
    int c = lane + t*64;
    split_store(v[t]*rs*w[c], hi, lo, row*384 + c);
  }
}

// ---------------- GEMM1: s_n @ [Wq|Wk|Wv|Wg], hi/lo 3-MFMA ----------------
__global__ __launch_bounds__(256) void gemm_qkvg(
    const unsigned short* __restrict__ Ah, const unsigned short* __restrict__ Al,
    const unsigned short* __restrict__ Bh, const unsigned short* __restrict__ Bl,
    const float* __restrict__ bg,
    unsigned short* __restrict__ q_hi, unsigned short* __restrict__ q_lo,
    unsigned short* __restrict__ k_hi, unsigned short* __restrict__ k_lo,
    unsigned short* __restrict__ v_hi, unsigned short* __restrict__ v_lo,
    float* __restrict__ g){
  __shared__ __align__(16) unsigned short lah[64*40], lal[64*40], lbh[64*40], lbl[64*40];
  int t = threadIdx.x, wv = t >> 6, lane = t & 63;
  int m0 = blockIdx.y * 64, n0 = blockIdx.x * 64;
  int fr = lane & 15, fg = lane >> 4;
  f32x4 z4 = {0.f,0.f,0.f,0.f};
  f32x4 acc[4] = {z4, z4, z4, z4};
  int sr = t >> 2, sc = (t & 3) << 3;
  for (int k0 = 0; k0 < 384; k0 += 32){
    *(short8*)&lah[sr*40 + sc] = *(const short8*)&Ah[(m0+sr)*384 + k0 + sc];
    *(short8*)&lal[sr*40 + sc] = *(const short8*)&Al[(m0+sr)*384 + k0 + sc];
    *(short8*)&lbh[sr*40 + sc] = *(const short8*)&Bh[(n0+sr)*384 + k0 + sc];
    *(short8*)&lbl[sr*40 + sc] = *(const short8*)&Bl[(n0+sr)*384 + k0 + sc];
    __syncthreads();
    short8 a_h = *(short8*)&lah[(wv*16+fr)*40 + (fg<<3)];
    short8 a_l = *(short8*)&lal[(wv*16+fr)*40 + (fg<<3)];
    #pragma unroll
    for (int cf=0; cf<4; cf++){
      short8 b_h = *(short8*)&lbh[(cf*16+fr)*40 + (fg<<3)];
      short8 b_l = *(short8*)&lbl[(cf*16+fr)*40 + (fg<<3)];
      acc[cf] = MFMA16(a_h, b_h, acc[cf]);
      acc[cf] = MFMA16(a_h, b_l, acc[cf]);
      acc[cf] = MFMA16(a_l, b_h, acc[cf]);
    }
    __syncthreads();
  }
  int sec = n0 / 384;
  int nb0 = n0 - sec*384;
  #pragma unroll
  for (int cf=0; cf<4; cf++){
    #pragma unroll
    for (int jj=0; jj<4; jj++){
      int row = m0 + wv*16 + (fg<<2) + jj;
      int nn = nb0 + cf*16 + fr;
      float val = acc[cf][jj];
      int hh = nn >> 5, dd = nn & 31;
      if (sec == 0)      split_store(val, q_hi, q_lo, (hh<<15) + (row<<5) + dd);
      else if (sec == 1) split_store(val, k_hi, k_lo, (hh<<15) + (row<<5) + dd);
      else if (sec == 2) split_store(val, v_hi, v_lo, (hh<<15) + dd*SQ + row);  // V transposed [h][d][j]
      else               g[row*384 + nn] = val + bg[nn];
    }
  }
}

// ---------------- bias kernel v5: MFMA head-projection, gld_lds16 staging ----------------
// Block = one i, 4 waves; wave w owns rows [w*256,(w+1)*256) in 8 subtiles of 32,
// double-buffered. B (=ww hi/lo bf16) lives in registers (loaded once). z staged
// via global_load_lds width=16 with source XOR-pre-swizzle (word ^= (row&7)<<2);
// ds_read_b128 applies the same XOR -> bank-even A-fragment reads. acc = z @ WW
// via 3-MFMA hi/lo; ssq on VALU; rs/mask via tiny wave-private LDS. Counted-vmcnt
// pipeline, no barriers.
__global__ __launch_bounds__(256) void bias_k(
    const float* __restrict__ z, const int* __restrict__ zm,
    const unsigned short* __restrict__ wwh, const unsigned short* __restrict__ wwl2,
    float* __restrict__ bias){
  __shared__ __align__(16) float zbuf[4*2*4096];   // 128KB: [wave][buf][32][128]
  __shared__ __align__(16) float mkbuf[1024];      // 4KB: [wave][256] masks
  __shared__ __align__(16) float rsbuf[4*32];      // 512B: [wave][32] rs
  int t = threadIdx.x, w = t >> 6, lane = t & 63;
  int i = blockIdx.x;
  int wbase = w << 8;
  int fr = lane & 15, fg = lane >> 4;
  const float* zi = z + (size_t)i * (SQ*128);

  // masks for this wave's 256 rows
  #pragma unroll
  for (int n=0; n<4; n++){
    int j = wbase + n*64 + lane;
    mkbuf[j] = (zm[i*SQ + j] != 0) ? 0.f : -1.0e9f;
  }
  // B fragments: b[e] = WW[c = kt*32+fg*8+e][h = fr], hi/lo
  short8 Bh[4], Bl[4];
  #pragma unroll
  for (int kt=0; kt<4; kt++){
    #pragma unroll
    for (int e=0; e<8; e++){
      int c = kt*32 + (fg<<3) + e;
      Bh[kt][e] = (short)wwh[(c<<4) + fr];
      Bl[kt][e] = (short)wwl2[(c<<4) + fr];
    }
  }

  int shalf = lane >> 5;            // row parity within a staging instr
  int cw = (lane & 31) << 2;        // word offset within row (0..124)

  #define STAGE(ST)                                                        \
    {                                                                      \
      const float* zs = zi + (size_t)(wbase + (ST)*32) * 128;              \
      float* db = zbuf + (w*2 + ((ST)&1))*4096;                            \
      _Pragma("unroll")                                                    \
      for (int n=0; n<16; ++n){                                            \
        int r = n*2 + shalf;                                               \
        gld_lds16(zs + r*128 + (cw ^ ((r&7)<<2)), db + n*256);             \
      }                                                                    \
    }

  STAGE(0)

  #pragma unroll 1
  for (int st = 0; st < 8; ++st){
    if (st < 7) STAGE(st+1)
    if (st == 0)      asm volatile("s_waitcnt vmcnt(16)" ::: "memory");
    else if (st == 7) asm volatile("s_waitcnt vmcnt(8)"  ::: "memory");
    else              asm volatile("s_waitcnt vmcnt(24)" ::: "memory");

    const int zb = (w*2 + (st&1))*4096;
    f32x4 acc0 = {0.f,0.f,0.f,0.f}, acc1 = {0.f,0.f,0.f,0.f};
    float ssq0 = 0.f, ssq1 = 0.f;
    int swz = (fr & 7) << 2;        // same for row fr and fr+16
    #pragma unroll
    for (int kt=0; kt<4; kt++){
      int c = kt*32 + (fg<<3);
      float4 u0  = *(const float4*)&zbuf[zb + fr*128        + (c ^ swz)];
      float4 u0b = *(const float4*)&zbuf[zb + fr*128        + ((c+4) ^ swz)];
      float4 u1  = *(const float4*)&zbuf[zb + (fr+16)*128   + (c ^ swz)];
      float4 u1b = *(const float4*)&zbuf[zb + (fr+16)*128   + ((c+4) ^ swz)];
      ssq0 = fmaf(u0.x,u0.x,ssq0);  ssq0 = fmaf(u0.y,u0.y,ssq0);
      ssq0 = fmaf(u0.z,u0.z,ssq0);  ssq0 = fmaf(u0.w,u0.w,ssq0);
      ssq0 = fmaf(u0b.x,u0b.x,ssq0); ssq0 = fmaf(u0b.y,u0b.y,ssq0);
      ssq0 = fmaf(u0b.z,u0b.z,ssq0); ssq0 = fmaf(u0b.w,u0b.w,ssq0);
      ssq1 = fmaf(u1.x,u1.x,ssq1);  ssq1 = fmaf(u1.y,u1.y,ssq1);
      ssq1 = fmaf(u1.z,u1.z,ssq1);  ssq1 = fmaf(u1.w,u1.w,ssq1);
      ssq1 = fmaf(u1b.x,u1b.x,ssq1); ssq1 = fmaf(u1b.y,u1b.y,ssq1);
      ssq1 = fmaf(u1b.z,u1b.z,ssq1); ssq1 = fmaf(u1b.w,u1b.w,ssq1);
      short8 ah0, al0, ah1, al1;
      #pragma unroll
      for (int e=0; e<8; e++){
        float f0 = (e<4) ? COMP4(u0, e) : COMP4(u0b, e-4);
        float f1 = (e<4) ? COMP4(u1, e) : COMP4(u1b, e-4);
        unsigned int x0 = __float_as_uint(f0), x1 = __float_as_uint(f1);
        ah0[e] = (short)(unsigned short)(x0 >> 16);
        ah1[e] = (short)(unsigned short)(x1 >> 16);
        float r0f = f0 - __uint_as_float(x0 & 0xffff0000u);
        float r1f = f1 - __uint_as_float(x1 & 0xffff0000u);
        al0[e] = (short)(unsigned short)(__float_as_uint(r0f) >> 16);
        al1[e] = (short)(unsigned short)(__float_as_uint(r1f) >> 16);
      }
      acc0 = MFMA16(ah0, Bh[kt], acc0);
      acc0 = MFMA16(ah0, Bl[kt], acc0);
      acc0 = MFMA16(al0, Bh[kt], acc0);
      acc1 = MFMA16(ah1, Bh[kt], acc1);
      acc1 = MFMA16(ah1, Bl[kt], acc1);
      acc1 = MFMA16(al1, Bh[kt], acc1);
    }
    // row ssq: reduce across fg (lane bits 4,5)
    ssq0 += __shfl_xor(ssq0, 16); ssq0 += __shfl_xor(ssq0, 32);
    ssq1 += __shfl_xor(ssq1, 16); ssq1 += __shfl_xor(ssq1, 32);
    if (lane < 16){
      rsbuf[w*32 + lane]      = rsqrtf(ssq0*(1.0f/128.0f) + 1e-5f);
      rsbuf[w*32 + 16 + lane] = rsqrtf(ssq1*(1.0f/128.0f) + 1e-5f);
    }
    int jo = fg << 2;
    float4 rs0 = *(const float4*)&rsbuf[w*32 + jo];
    float4 rs1 = *(const float4*)&rsbuf[w*32 + 16 + jo];
    float4 mk0 = *(const float4*)&mkbuf[wbase + st*32 + jo];
    float4 mk1 = *(const float4*)&mkbuf[wbase + st*32 + 16 + jo];
    if (fr < 12){
      size_t hb = (size_t)fr*((size_t)SQ*SQ) + (size_t)i*SQ + (size_t)(wbase + st*32);
      #pragma unroll
      for (int jj=0; jj<4; jj++){
        bias[hb + jo + jj]      = fmaf(acc0[jj], COMP4(rs0,jj), COMP4(mk0,jj));
        bias[hb + 16 + jo + jj] = fmaf(acc1[jj], COMP4(rs1,jj), COMP4(mk1,jj));
      }
    }
  }
  #undef STAGE
}

// ---------------- attention: wave-private 4 rows, no barriers ----------------
__global__ __launch_bounds__(256) void attn_k(
    const unsigned short* __restrict__ qh_, const unsigned short* __restrict__ ql_,
    const unsigned short* __restrict__ kh_, const unsigned short* __restrict__ kl_,
    const unsigned short* __restrict__ vh_, const unsigned short* __restrict__ vl_,
    const float* __restrict__ bias,
    unsigned short* __restrict__ oh_, unsigned short* __restrict__ ol_){
  __shared__ __align__(16) float Sl[16][SQ];   // exactly 64 KB, rows wave-private
  int t = threadIdx.x, wv = t >> 6, lane = t & 63;
  int h = blockIdx.x >> 6;
  int i0 = (blockIdx.x & 63) << 4;
  int fr = lane & 15, fg = lane >> 4;
  int hbase = h << 15;
  const unsigned short* qh = qh_ + hbase; const unsigned short* ql = ql_ + hbase;
  const unsigned short* kh = kh_ + hbase; const unsigned short* kl = kl_ + hbase;
  const unsigned short* vh = vh_ + hbase; const unsigned short* vl = vl_ + hbase;
  int r0 = i0 + (wv << 2);

  short8 aqh = {0,0,0,0,0,0,0,0}, aql = {0,0,0,0,0,0,0,0};
  if (fr < 4){
    aqh = *(const short8*)&qh[((r0 + fr) << 5) + (fg << 3)];
    aql = *(const short8*)&ql[((r0 + fr) << 5) + (fg << 3)];
  }
  const float scale = 0.17677669529663687f;  // 1/sqrt(32)

  // QK^T (hi/lo 3-MFMA) + bias + mask -> Sl
  for (int jt = 0; jt < 64; jt++){
    int j0 = jt << 4;
    short8 bkh = *(const short8*)&kh[((j0 + fr) << 5) + (fg << 3)];
    short8 bkl = *(const short8*)&kl[((j0 + fr) << 5) + (fg << 3)];
    f32x4 a = {0.f,0.f,0.f,0.f};
    a = MFMA16(aqh, bkh, a);
    a = MFMA16(aqh, bkl, a);
    a = MFMA16(aql, bkh, a);
    if (lane < 16){
      #pragma unroll
      for (int rr=0; rr<4; rr++){
        float b = bias[(size_t)h*((size_t)SQ*SQ) + (size_t)(r0+rr)*SQ + j0 + lane];
        Sl[(wv<<2)+rr][j0+lane] = fmaf(a[rr], scale, b);
      }
    }
  }

  // softmax: row = fg (4 rows/wave, 16 lanes/row); bank-rotated scans
  float* Sr = &Sl[(wv<<2)+fg][0];
  float mx = -3.0e38f;
  for (int tt=0; tt<64; tt++){
    int j = (fr + (tt<<4) + (fg<<3)) & 1023;
    mx = fmaxf(mx, Sr[j]);
  }
  mx = fmaxf(mx, __shfl_xor(mx, 1));
  mx = fmaxf(mx, __shfl_xor(mx, 2));
  mx = fmaxf(mx, __shfl_xor(mx, 4));
  mx = fmaxf(mx, __shfl_xor(mx, 8));
  float sm = 0.f;
  for (int tt=0; tt<64; tt++){
    int j = (fr + (tt<<4) + (fg<<3)) & 1023;
    float e = __expf(Sr[j] - mx);
    sm += e;
    Sr[j] = e;   // store unnormalized P (fp32)
  }
  sm += __shfl_xor(sm, 1);
  sm += __shfl_xor(sm, 2);
  sm += __shfl_xor(sm, 4);
  sm += __shfl_xor(sm, 8);
  float linv = 1.0f / sm;
  float li0 = __shfl(linv, 0), li1 = __shfl(linv, 16), li2 = __shfl(linv, 32), li3 = __shfl(linv, 48);

  // PV (hi/lo 3-MFMA), exp values read from LDS, split to bf16 on the fly
  f32x4 o0 = {0.f,0.f,0.f,0.f}, o1 = {0.f,0.f,0.f,0.f};
  for (int k0 = 0; k0 < SQ; k0 += 32){
    float4 pa = {0.f,0.f,0.f,0.f}, pb = {0.f,0.f,0.f,0.f};
    if (fr < 4){
      const float* pp = &Sl[(wv<<2)+fr][k0 + (fg<<3)];
      pa = *(const float4*)pp;
      pb = *(const float4*)(pp+4);
    }
    short8 ph = {0,0,0,0,0,0,0,0}, pl = {0,0,0,0,0,0,0,0};
    #pragma unroll
    for (int e2=0; e2<8; e2++){
      float pv = (e2 < 4) ? COMP4(pa, e2) : COMP4(pb, (e2-4));
      unsigned short hbv = f2bf(pv);
      ph[e2] = (short)hbv;
      pl[e2] = (short)f2bf(pv - bf2f(hbv));
    }
    short8 v0h = *(const short8*)&vh[(fr)*SQ + k0 + (fg<<3)];
    short8 v0l = *(const short8*)&vl[(fr)*SQ + k0 + (fg<<3)];
    short8 v1h = *(const short8*)&vh[(16+fr)*SQ + k0 + (fg<<3)];
    short8 v1l = *(const short8*)&vl[(16+fr)*SQ + k0 + (fg<<3)];
    o0 = MFMA16(ph, v0h, o0); o0 = MFMA16(ph, v0l, o0); o0 = MFMA16(pl, v0h, o0);
    o1 = MFMA16(ph, v1h, o1); o1 = MFMA16(ph, v1l, o1); o1 = MFMA16(pl, v1h, o1);
  }
  float liA[4] = {li0, li1, li2, li3};
  if (lane < 16){
    #pragma unroll
    for (int rr=0; rr<4; rr++){
      int orow = r0 + rr;
      float va = o0[rr] * liA[rr];
      float vb = o1[rr] * liA[rr];
      split_store(va, oh_, ol_, orow*384 + (h<<5) + fr);
      split_store(vb, oh_, ol_, orow*384 + (h<<5) + 16 + fr);
    }
  }
}

// ---------------- GEMM2: (o @ Wo + bo) * g -> fp32 out ----------------
__global__ __launch_bounds__(256) void gemm_out_k(
    const unsigned short* __restrict__ Ah, const unsigned short* __restrict__ Al,
    const unsigned short* __restrict__ Bh, const unsigned short* __restrict__ Bl,
    const float* __restrict__ bo, const float* __restrict__ g,
    float* __restrict__ out){
  __shared__ __align__(16) unsigned short lah[64*40], lal[64*40], lbh[64*40], lbl[64*40];
  int t = threadIdx.x, wv = t >> 6, lane = t & 63;
  int m0 = blockIdx.y * 64, n0 = blockIdx.x * 64;
  int fr = lane & 15, fg = lane >> 4;
  f32x4 z4 = {0.f,0.f,0.f,0.f};
  f32x4 acc[4] = {z4, z4, z4, z4};
  int sr = t >> 2, sc = (t & 3) << 3;
  for (int k0 = 0; k0 < 384; k0 += 32){
    *(short8*)&lah[sr*40 + sc] = *(const short8*)&Ah[(m0+sr)*384 + k0 + sc];
    *(short8*)&lal[sr*40 + sc] = *(const short8*)&Al[(m0+sr)*384 + k0 + sc];
    *(short8*)&lbh[sr*40 + sc] = *(const short8*)&Bh[(n0+sr)*384 + k0 + sc];
    *(short8*)&lbl[sr*40 + sc] = *(const short8*)&Bl[(n0+sr)*384 + k0 + sc];
    __syncthreads();
    short8 a_h = *(short8*)&lah[(wv*16+fr)*40 + (fg<<3)];
    short8 a_l = *(short8*)&lal[(wv*16+fr)*40 + (fg<<3)];
    #pragma unroll
    for (int cf=0; cf<4; cf++){
      short8 b_h = *(short8*)&lbh[(cf*16+fr)*40 + (fg<<3)];
      short8 b_l = *(short8*)&lbl[(cf*16+fr)*40 + (fg<<3)];
      acc[cf] = MFMA16(a_h, b_h, acc[cf]);
      acc[cf] = MFMA16(a_h, b_l, acc[cf]);
      acc[cf] = MFMA16(a_l, b_h, acc[cf]);
    }
    __syncthreads();
  }
  #pragma unroll
  for (int cf=0; cf<4; cf++){
    #pragma unroll
    for (int jj=0; jj<4; jj++){
      int row = m0 + wv*16 + (fg<<2) + jj;
      int col = n0 + cf*16 + fr;
      out[row*384 + col] = (acc[cf][jj] + bo[col]) * g[row*384 + col];
    }
  }
}

// ---------------- launch ----------------
extern "C" void kernel_launch(void* const* d_in, const int* in_sizes, int n_in,
                              void* d_out, int out_size, void* d_ws, size_t ws_size,
                              hipStream_t stream) {
  const float* s   = (const float*)d_in[0];
  const float* z   = (const float*)d_in[1];
  const int*   zm  = (const int*)d_in[2];
  const float* w_s = (const float*)d_in[3];
  const float* w_z = (const float*)d_in[4];
  const float* Wz  = (const float*)d_in[5];
  const float* Wq  = (const float*)d_in[6];
  const float* Wk  = (const float*)d_in[7];
  const float* Wv  = (const float*)d_in[8];
  const float* Wg  = (const float*)d_in[9];
  const float* bg  = (const float*)d_in[10];
  const float* Wo  = (const float*)d_in[11];
  const float* bo  = (const float*)d_in[12];
  float* out = (float*)d_out;
  char* ws = (char*)d_ws;

  unsigned short* s_hi  = (unsigned short*)(ws + 0);
  unsigned short* s_lo  = (unsigned short*)(ws + 786432);
  unsigned short* wt_hi = (unsigned short*)(ws + 1572864);   // [1920][384]
  unsigned short* wt_lo = (unsigned short*)(ws + 3047424);
  unsigned short* wwh   = (unsigned short*)(ws + 4521984);   // [128][16] bf16 hi
  unsigned short* wwl2  = (unsigned short*)(ws + 4526080);   // [128][16] bf16 lo
  unsigned short* q_hi  = (unsigned short*)(ws + 4532224);   // [12][1024][32]
  unsigned short* q_lo  = (unsigned short*)(ws + 5318656);
  unsigned short* k_hi  = (unsigned short*)(ws + 6105088);
  unsigned short* k_lo  = (unsigned short*)(ws + 6891520);
  unsigned short* v_hi  = (unsigned short*)(ws + 7677952);   // [12][32][1024] (transposed)
  unsigned short* v_lo  = (unsigned short*)(ws + 8464384);
  float*          gbuf  = (float*)(ws + 9250816);            // [1024][384] fp32
  unsigned short* o_hi  = (unsigned short*)(ws + 10823680);  // [1024][384]
  unsigned short* o_lo  = (unsigned short*)(ws + 11610112);
  float*          biasb = (float*)(ws + 12396544);           // [12][1024][1024] fp32, 48MB

  prep_wt<<<dim3(60,12), dim3(32,8), 0, stream>>>(Wq, Wk, Wv, Wg, Wo, wt_hi, wt_lo);
  prep_ww<<<8, 256, 0, stream>>>(w_z, Wz, wwh, wwl2);
  rmsnorm_s<<<256, 256, 0, stream>>>(s, w_s, s_hi, s_lo);
  gemm_qkvg<<<dim3(24,16), 256, 0, stream>>>(s_hi, s_lo, wt_hi, wt_lo, bg,
                                             q_hi, q_lo, k_hi, k_lo, v_hi, v_lo, gbuf);
  bias_k<<<1024, 256, 0, stream>>>(z, zm, wwh, wwl2, biasb);
  attn_k<<<768, 256, 0, stream>>>(q_hi, q_lo, k_hi, k_lo, v_hi, v_lo, biasb, o_hi, o_lo);
  gemm_out_k<<<dim3(6,16), 256, 0, stream>>>(o_hi, o_lo,
                                             wt_hi + 1536*384, wt_lo + 1536*384,
                                             bo, gbuf, out);
}